// Round 7
// baseline (312.757 us; speedup 1.0000x reference)
//
#include <hip/hip_runtime.h>
#include <hip/hip_bf16.h>

// Problem: B=4, T=1024, C=1024, H=16, D=64, MAX_LEN=1024, NPOS=2047
// Pipeline:
//   prep: merged cvt(x,qkv_w,proj_w)->bf16 + table_reduce rel_pos_emb->(2047,16)
//   gemm_bt<0>: qkv = x @ qkv_w^T + b -> scatter bf16; Q,K as (B,H,T,D), V as (B,H,D,T)
//   attn_mfma: flash causal, 128-query blocks (8 waves), MFMA QK^T/PV -> y (B,T,C) bf16
//   gemm_bt<1>: out = y @ proj_w^T + b -> fp32 d_out
//
// gemm_bt R7: 128x128 tile, BK=32, LDS double-buffer with PREFETCH DISTANCE 2.
// R4/R5 both had distance-1 prefetch -> every iteration's ds_write waited
// ~full global-load latency (L3 ~600-900cyc), pinning MfmaUtil at ~14%.
// Now: iter k issues loads for tile k+2, ds_writes tile k+1's regs (loaded a
// full iteration ago -> vmcnt leaves new loads in flight), computes tile k.
// One barrier per iteration.
//
// Workspace layout (bytes):
//   xb   @ 0         : 4096x1024 bf16  (8 MB)
//   wb   @ 8388608   : 3072x1024 bf16  (6 MB)
//   pwb  @ 14680064  : 1024x1024 bf16  (2 MB)
//   table@ 16777216  : 2047x16 f32     (128 KB)
//   qkvb @ 16908288  : (3,4,16,64K) bf16 (24 MB)
//   y    @ 42074112  : 4096x1024 bf16  (8 MB)

typedef __bf16 bf16x8 __attribute__((ext_vector_type(8)));
typedef float f32x4 __attribute__((ext_vector_type(4)));

__device__ __forceinline__ float bf2f(unsigned short u) {
    return __uint_as_float(((unsigned)u) << 16);
}
__device__ __forceinline__ unsigned short f2bf(float f) {
    __hip_bfloat16 h = __float2bfloat16(f);
    return *reinterpret_cast<unsigned short*>(&h);
}

// ---------------- merged preprocessing: cvt x/qkv_w/proj_w + rel-pos table ----------------
__global__ __launch_bounds__(256) void prep(const float* __restrict__ x,
                                            const float* __restrict__ w,
                                            const float* __restrict__ pw,
                                            const float* __restrict__ rel,
                                            unsigned short* __restrict__ xb,
                                            unsigned short* __restrict__ wb,
                                            unsigned short* __restrict__ pwb,
                                            float* __restrict__ table) {
    const int bid = blockIdx.x;
    const int tid = threadIdx.x;
    if (bid < 8192) {
        const float* in;
        unsigned short* out;
        int base;
        if (bid < 4096)      { in = x;  out = xb;  base = bid * 1024; }
        else if (bid < 7168) { in = w;  out = wb;  base = (bid - 4096) * 1024; }
        else                 { in = pw; out = pwb; base = (bid - 7168) * 1024; }
        const int i = base + tid * 4;
        float4 v = *(const float4*)(in + i);
        out[i]     = f2bf(v.x);
        out[i + 1] = f2bf(v.y);
        out[i + 2] = f2bf(v.z);
        out[i + 3] = f2bf(v.w);
    } else {
        const int p = bid - 8192;  // 0..2046
        const int lane = tid & 63, wave = tid >> 6;
        const float* r = rel + (size_t)p * 1024;
        float s[4];
#pragma unroll
        for (int k = 0; k < 4; ++k) s[k] = r[tid + 256 * k];
#pragma unroll
        for (int k = 0; k < 4; ++k) {
            float v = s[k];
            for (int o = 32; o; o >>= 1) v += __shfl_xor(v, o, 64);
            if (lane == 0) table[p * 16 + wave + 4 * k] = v;
        }
    }
}

// ---------------- bf16 MFMA GEMM: C = A B^T + bias, dist-2 prefetch dbuf ----------------
// Staging: thread t owns row t>>1, 32B chunk (t&1)*32B: 2 int4 global loads
// + 2 ds_write_b128 per operand. EPI=0: scatter bf16 into qkv planes
// (Q,K [t][d], V [d][t]). EPI=1: fp32 row-major out.

#define GEMM_STEP(KK, WRS, LDSI, CB)                                                     \
    {                                                                                    \
        __syncthreads();                                                                 \
        if ((KK) + 64 < K) {                                                             \
            pa[LDSI][0] = *(const int4*)(Ap + (KK) + 64);                                \
            pa[LDSI][1] = *(const int4*)(Ap + (KK) + 72);                                \
            pb[LDSI][0] = *(const int4*)(Bp + (KK) + 64);                                \
            pb[LDSI][1] = *(const int4*)(Bp + (KK) + 72);                                \
        }                                                                                \
        bf16x8 af[4], bfr[4];                                                            \
        _Pragma("unroll") for (int r = 0; r < 4; ++r)                                    \
            af[r] = *(const bf16x8*)(&As[CB][(64 * wr + 16 * r + lm) * 40 + quad * 8]);  \
        _Pragma("unroll") for (int c = 0; c < 4; ++c)                                    \
            bfr[c] = *(const bf16x8*)(&Bs[CB][(64 * wc + 16 * c + lm) * 40 + quad * 8]); \
        _Pragma("unroll") for (int r = 0; r < 4; ++r)                                    \
            _Pragma("unroll") for (int c = 0; c < 4; ++c)                                \
                acc[r][c] = __builtin_amdgcn_mfma_f32_16x16x32_bf16(af[r], bfr[c],       \
                                                                    acc[r][c], 0, 0, 0);\
        if ((KK) + 32 < K) {                                                             \
            *(int4*)(&As[(CB) ^ 1][woff])     = pa[WRS][0];                              \
            *(int4*)(&As[(CB) ^ 1][woff] + 8) = pa[WRS][1];                              \
            *(int4*)(&Bs[(CB) ^ 1][woff])     = pb[WRS][0];                              \
            *(int4*)(&Bs[(CB) ^ 1][woff] + 8) = pb[WRS][1];                              \
        }                                                                                \
    }

template <int EPI>
__global__ __launch_bounds__(256) void gemm_bt(const unsigned short* __restrict__ A,
                                               const unsigned short* __restrict__ Bm,
                                               const float* __restrict__ bias,
                                               unsigned short* __restrict__ outb,
                                               float* __restrict__ outf,
                                               int M, int N, int K) {
    __shared__ __attribute__((aligned(16))) unsigned short As[2][128 * 40];
    __shared__ __attribute__((aligned(16))) unsigned short Bs[2][128 * 40];
    const int bm = blockIdx.x * 128, bn = blockIdx.y * 128;
    const int tid = threadIdx.x, lane = tid & 63, wave = tid >> 6;
    const int wr = wave & 1, wc = wave >> 1;
    const int quad = lane >> 4, lm = lane & 15;

    const int srow = tid >> 1;        // 0..127
    const int scol = (tid & 1) * 16;  // shorts
    const unsigned short* Ap = A + (size_t)(bm + srow) * K + scol;
    const unsigned short* Bp = Bm + (size_t)(bn + srow) * K + scol;
    const int woff = srow * 40 + scol;

    f32x4 acc[4][4];
#pragma unroll
    for (int r = 0; r < 4; ++r)
#pragma unroll
        for (int c = 0; c < 4; ++c) acc[r][c] = (f32x4){0.f, 0.f, 0.f, 0.f};

    int4 pa[2][2], pb[2][2];
    // prologue: tile 0 -> set0 -> LDS0; tile 1 -> set1 (in flight)
    pa[0][0] = *(const int4*)(Ap);
    pa[0][1] = *(const int4*)(Ap + 8);
    pb[0][0] = *(const int4*)(Bp);
    pb[0][1] = *(const int4*)(Bp + 8);
    *(int4*)(&As[0][woff])     = pa[0][0];
    *(int4*)(&As[0][woff] + 8) = pa[0][1];
    *(int4*)(&Bs[0][woff])     = pb[0][0];
    *(int4*)(&Bs[0][woff] + 8) = pb[0][1];
    pa[1][0] = *(const int4*)(Ap + 32);
    pa[1][1] = *(const int4*)(Ap + 40);
    pb[1][0] = *(const int4*)(Bp + 32);
    pb[1][1] = *(const int4*)(Bp + 40);

    // iter k (tile kk/32): barrier; load tile k+2 -> set[k&1]; MFMA from buf[k&1];
    // ds_write tile k+1 (set[(k+1)&1], loaded one full iter ago) -> buf[(k&1)^1].
    for (int kk = 0; kk < K; kk += 64) {
        GEMM_STEP(kk,      1, 0, 0);
        GEMM_STEP(kk + 32, 0, 1, 1);
    }

    // C/D layout: col = lane&15, row = (lane>>4)*4 + reg
#pragma unroll
    for (int r = 0; r < 4; ++r)
#pragma unroll
        for (int c = 0; c < 4; ++c)
#pragma unroll
            for (int i = 0; i < 4; ++i) {
                const int row = bm + 64 * wr + 16 * r + quad * 4 + i;
                const int col = bn + 64 * wc + 16 * c + lm;
                const float v = acc[r][c][i] + bias[col];
                if (EPI == 0) {
                    const int b = row >> 10, t = row & 1023;
                    const int s3 = col >> 10, rem = col & 1023;
                    const int h = rem >> 6, d = rem & 63;
                    const size_t base = (((size_t)s3 * 4 + b) * 16 + h) * 65536;
                    const size_t off = base + (s3 == 2 ? (size_t)d * 1024 + t
                                                       : (size_t)t * 64 + d);
                    outb[off] = f2bf(v);
                } else {
                    outf[(size_t)row * N + col] = v;
                }
            }
}

// ---------------- MFMA flash causal attention, 128-query blocks ----------------
__global__ __launch_bounds__(512) void attn_mfma(const unsigned short* __restrict__ qkvb,
                                                 const float* __restrict__ table,
                                                 unsigned short* __restrict__ y) {
    const int bh = blockIdx.x, b = bh >> 4, h = bh & 15;
    const int qb = (7 - blockIdx.y) * 128;  // longest blocks first
    const int tid = threadIdx.x, lane = tid & 63, wave = tid >> 6;
    const int quad = lane >> 4, lm = lane & 15;

    __shared__ __attribute__((aligned(16))) unsigned short Ks[64][72];      // [j][d]
    __shared__ __attribute__((aligned(16))) unsigned short Vs[64][72];      // [d][j] (V^T)
    __shared__ __attribute__((aligned(16))) unsigned short Ps[8][16][72];   // per-wave P
    __shared__ float tb[1280];

    const unsigned short* Qg  = qkvb + ((size_t)(b)*16 + h) * 65536;       // [t][d]
    const unsigned short* Kg  = qkvb + ((size_t)(4 + b)*16 + h) * 65536;   // [t][d]
    const unsigned short* Vtg = qkvb + ((size_t)(8 + b)*16 + h) * 65536;   // [d][t]

    const bf16x8 qf0 = *(const bf16x8*)(Qg + (size_t)(qb + wave * 16 + lm) * 64 + quad * 8);
    const bf16x8 qf1 = *(const bf16x8*)(Qg + (size_t)(qb + wave * 16 + lm) * 64 + 32 + quad * 8);

    const int tbn = qb + 255;
    for (int i = tid; i < tbn; i += 512) tb[i] = table[(896 + i) * 16 + h];

    f32x4 oacc[4];
#pragma unroll
    for (int nb = 0; nb < 4; ++nb) oacc[nb] = (f32x4){0.f, 0.f, 0.f, 0.f};
    float mi[4], li[4];
#pragma unroll
    for (int i = 0; i < 4; ++i) { mi[i] = -1e30f; li[i] = 0.f; }

    const int ktiles = qb / 64 + 2;
    for (int kt = 0; kt < ktiles; ++kt) {
        __syncthreads();
        {
            const int r0 = tid >> 3, c0 = (tid & 7) * 8;
            *(int4*)&Ks[r0][c0] = *(const int4*)(Kg + (size_t)(kt * 64 + r0) * 64 + c0);
            *(int4*)&Vs[r0][c0] = *(const int4*)(Vtg + (size_t)r0 * 1024 + kt * 64 + c0);
        }
        __syncthreads();

        f32x4 s[4];
#pragma unroll
        for (int nb = 0; nb < 4; ++nb) {
            bf16x8 k0 = *(const bf16x8*)(&Ks[nb * 16 + lm][quad * 8]);
            bf16x8 k1 = *(const bf16x8*)(&Ks[nb * 16 + lm][32 + quad * 8]);
            s[nb] = (f32x4){0.f, 0.f, 0.f, 0.f};
            s[nb] = __builtin_amdgcn_mfma_f32_16x16x32_bf16(qf0, k0, s[nb], 0, 0, 0);
            s[nb] = __builtin_amdgcn_mfma_f32_16x16x32_bf16(qf1, k1, s[nb], 0, 0, 0);
        }

        const int qrow0 = qb + wave * 16 + quad * 4;
        const int jbase = kt * 64 + lm;
#pragma unroll
        for (int nb = 0; nb < 4; ++nb)
#pragma unroll
            for (int i = 0; i < 4; ++i) {
                const int q = qrow0 + i, j = jbase + nb * 16;
                const float v = fmaf(s[nb][i], 0.125f, tb[q - j + 127]);
                s[nb][i] = (j <= q) ? v : -1e30f;
            }

        float mnew[4], al[4];
#pragma unroll
        for (int i = 0; i < 4; ++i) {
            float mx = fmaxf(fmaxf(s[0][i], s[1][i]), fmaxf(s[2][i], s[3][i]));
            mx = fmaxf(mx, __shfl_xor(mx, 1, 64));
            mx = fmaxf(mx, __shfl_xor(mx, 2, 64));
            mx = fmaxf(mx, __shfl_xor(mx, 4, 64));
            mx = fmaxf(mx, __shfl_xor(mx, 8, 64));
            mnew[i] = fmaxf(mi[i], mx);
            al[i] = __expf(mi[i] - mnew[i]);
            mi[i] = mnew[i];
        }
#pragma unroll
        for (int nb = 0; nb < 4; ++nb)
#pragma unroll
            for (int i = 0; i < 4; ++i) s[nb][i] = __expf(s[nb][i] - mnew[i]);
#pragma unroll
        for (int i = 0; i < 4; ++i) {
            float sm = (s[0][i] + s[1][i]) + (s[2][i] + s[3][i]);
            sm += __shfl_xor(sm, 1, 64);
            sm += __shfl_xor(sm, 2, 64);
            sm += __shfl_xor(sm, 4, 64);
            sm += __shfl_xor(sm, 8, 64);
            li[i] = li[i] * al[i] + sm;
        }

#pragma unroll
        for (int nb = 0; nb < 4; ++nb)
#pragma unroll
            for (int i = 0; i < 4; ++i)
                Ps[wave][quad * 4 + i][nb * 16 + lm] = f2bf(s[nb][i]);

#pragma unroll
        for (int nb = 0; nb < 4; ++nb)
#pragma unroll
            for (int i = 0; i < 4; ++i) oacc[nb][i] *= al[i];

        const bf16x8 p0 = *(const bf16x8*)(&Ps[wave][lm][quad * 8]);
        const bf16x8 p1 = *(const bf16x8*)(&Ps[wave][lm][32 + quad * 8]);
#pragma unroll
        for (int nb = 0; nb < 4; ++nb) {
            bf16x8 v0 = *(const bf16x8*)(&Vs[nb * 16 + lm][quad * 8]);
            bf16x8 v1 = *(const bf16x8*)(&Vs[nb * 16 + lm][32 + quad * 8]);
            oacc[nb] = __builtin_amdgcn_mfma_f32_16x16x32_bf16(p0, v0, oacc[nb], 0, 0, 0);
            oacc[nb] = __builtin_amdgcn_mfma_f32_16x16x32_bf16(p1, v1, oacc[nb], 0, 0, 0);
        }
    }

    float inv[4];
#pragma unroll
    for (int i = 0; i < 4; ++i) inv[i] = 1.0f / li[i];
#pragma unroll
    for (int nb = 0; nb < 4; ++nb)
#pragma unroll
        for (int i = 0; i < 4; ++i) {
            const int q = qb + wave * 16 + quad * 4 + i;
            const int d = nb * 16 + lm;
            y[((size_t)(b * 1024 + q)) * 1024 + h * 64 + d] = f2bf(oacc[nb][i] * inv[i]);
        }
}

extern "C" void kernel_launch(void* const* d_in, const int* in_sizes, int n_in,
                              void* d_out, int out_size, void* d_ws, size_t ws_size,
                              hipStream_t stream) {
    const float* x      = (const float*)d_in[0];
    const float* qkv_w  = (const float*)d_in[1];
    const float* qkv_b  = (const float*)d_in[2];
    const float* proj_w = (const float*)d_in[3];
    const float* proj_b = (const float*)d_in[4];
    const float* rel    = (const float*)d_in[5];
    float* out = (float*)d_out;

    char* ws = (char*)d_ws;
    unsigned short* xb   = (unsigned short*)(ws);
    unsigned short* wb   = (unsigned short*)(ws + 8388608);
    unsigned short* pwb  = (unsigned short*)(ws + 14680064);
    float* table         = (float*)(ws + 16777216);
    unsigned short* qkvb = (unsigned short*)(ws + 16908288);
    unsigned short* yb   = (unsigned short*)(ws + 42074112);

    prep<<<10239, 256, 0, stream>>>(x, qkv_w, proj_w, rel, xb, wb, pwb, table);
    gemm_bt<0><<<dim3(32, 24), 256, 0, stream>>>(xb, wb, qkv_b, qkvb, nullptr, 4096, 3072, 1024);
    attn_mfma<<<dim3(64, 8), 512, 0, stream>>>(qkvb, table, yb);
    gemm_bt<1><<<dim3(32, 8), 256, 0, stream>>>(yb, pwb, proj_b, nullptr, out, 4096, 1024, 1024);
}

// Round 8
// 205.606 us; speedup vs baseline: 1.5211x; 1.5211x over previous
//
#include <hip/hip_runtime.h>
#include <hip/hip_bf16.h>

// Problem: B=4, T=1024, C=1024, H=16, D=64, MAX_LEN=1024, NPOS=2047
// Pipeline:
//   table_reduce rel_pos_emb -> (2047,16)
//   gemm_bt<0,f32A>: qkv = x @ qkv_w^T + b (cvt fused into staging) -> scatter bf16;
//                    Q,K as (B,H,T,D), V as (B,H,D,T)
//   attn_mfma: flash causal, 128-query blocks (8 waves), MFMA QK^T/PV -> y (B,T,C) bf16
//   gemm_bt<1,bf16A>: out = y @ proj_w^T + b (proj_w cvt fused) -> fp32 d_out
//
// gemm_bt R8: 128x128 tile, BK=32, *8 waves* (512 thr). Each wave = 64x32
// quadrant (4x2 16x16x32 MFMA). Rationale: R2-R7 showed MfmaUtil pinned ~14%
// with 4 waves/block -- exposed global-load latency with no wave surplus to
// hide it (m114 overlap needs spare waves). 8 waves doubles SIMD-mates.
// Staging: R4 discipline -- NAMED scalar prefetch regs, dist-1 (R7's indexed
// reg arrays spilled to scratch: WRITE_SIZE 24->250 MB). fp32->bf16 cvt fused
// into the ds_write (kills the separate prep pass).
//
// Workspace layout (bytes):
//   table@ 16777216  : 2047x16 f32     (128 KB)
//   qkvb @ 16908288  : (3,4,16,64K) bf16 (24 MB)
//   y    @ 42074112  : 4096x1024 bf16  (8 MB)

typedef __bf16 bf16x8 __attribute__((ext_vector_type(8)));
typedef float f32x4 __attribute__((ext_vector_type(4)));

__device__ __forceinline__ float bf2f(unsigned short u) {
    return __uint_as_float(((unsigned)u) << 16);
}
__device__ __forceinline__ unsigned short f2bf(float f) {
    __hip_bfloat16 h = __float2bfloat16(f);
    return *reinterpret_cast<unsigned short*>(&h);
}
__device__ __forceinline__ int4 cvt8(float4 a, float4 b) {
    union { unsigned short s[8]; int4 v; } u;
    u.s[0] = f2bf(a.x); u.s[1] = f2bf(a.y); u.s[2] = f2bf(a.z); u.s[3] = f2bf(a.w);
    u.s[4] = f2bf(b.x); u.s[5] = f2bf(b.y); u.s[6] = f2bf(b.z); u.s[7] = f2bf(b.w);
    return u.v;
}

// ---------------- rel_pos_emb (2047,1024) -> table (2047,16) ----------------
__global__ __launch_bounds__(256) void table_reduce(const float* __restrict__ rel,
                                                    float* __restrict__ table) {
    const int p = blockIdx.x;
    const int tid = threadIdx.x, lane = tid & 63, wave = tid >> 6;
    const float* r = rel + (size_t)p * 1024;
    float s[4];
#pragma unroll
    for (int k = 0; k < 4; ++k) s[k] = r[tid + 256 * k];
#pragma unroll
    for (int k = 0; k < 4; ++k) {
        float v = s[k];
        for (int o = 32; o; o >>= 1) v += __shfl_xor(v, o, 64);
        if (lane == 0) table[p * 16 + wave + 4 * k] = v;
    }
}

// ---------------- bf16 MFMA GEMM: C = A B^T + bias ----------------
// 512 threads, 8 waves: wr=wave&1 (64-row half), wc=wave>>1 (32-col quarter).
// Staging: thread t -> row t>>2, 8-short chunk (t&3)*8; A fp32 (AF32) loads
// 2 float4 + cvt, else 1 int4; B always fp32 + cvt.
// EPI=0: scatter bf16 into qkv planes (Q,K [t][d], V [d][t]). EPI=1: fp32 out.
template <int EPI, bool AF32>
__global__ __launch_bounds__(512) void gemm_bt(const void* __restrict__ Ain,
                                               const float* __restrict__ Bf,
                                               const float* __restrict__ bias,
                                               unsigned short* __restrict__ outb,
                                               float* __restrict__ outf,
                                               int M, int N, int K) {
    __shared__ __attribute__((aligned(16))) unsigned short As[128 * 40];
    __shared__ __attribute__((aligned(16))) unsigned short Bs[128 * 40];
    const int bm = blockIdx.x * 128, bn = blockIdx.y * 128;
    const int tid = threadIdx.x, lane = tid & 63, wave = tid >> 6;
    const int wr = wave & 1, wc = wave >> 1;  // wc in 0..3
    const int quad = lane >> 4, lm = lane & 15;

    const int srow = tid >> 2;        // 0..127
    const int scol = (tid & 3) * 8;   // shorts / elements
    const float* ApF          = (const float*)Ain + (size_t)(bm + srow) * K + scol;
    const unsigned short* ApH = (const unsigned short*)Ain + (size_t)(bm + srow) * K + scol;
    const float* BpF          = Bf + (size_t)(bn + srow) * K + scol;
    unsigned short* AsW = &As[srow * 40 + scol];
    unsigned short* BsW = &Bs[srow * 40 + scol];

    f32x4 acc[4][2];
#pragma unroll
    for (int r = 0; r < 4; ++r)
#pragma unroll
        for (int c = 0; c < 2; ++c) acc[r][c] = (f32x4){0.f, 0.f, 0.f, 0.f};

    // prologue prefetch of tile 0 (named scalars -- no indexed reg arrays!)
    float4 paf0, paf1, pbf0, pbf1;
    int4 pah;
    if (AF32) {
        paf0 = *(const float4*)(ApF);
        paf1 = *(const float4*)(ApF + 4);
    } else {
        pah = *(const int4*)(ApH);
    }
    pbf0 = *(const float4*)(BpF);
    pbf1 = *(const float4*)(BpF + 4);

    for (int kk = 0; kk < K; kk += 32) {
        // drain prefetch into LDS (cvt fused)
        *(int4*)(AsW) = AF32 ? cvt8(paf0, paf1) : pah;
        *(int4*)(BsW) = cvt8(pbf0, pbf1);
        __syncthreads();

        if (kk + 32 < K) {
            if (AF32) {
                paf0 = *(const float4*)(ApF + kk + 32);
                paf1 = *(const float4*)(ApF + kk + 36);
            } else {
                pah = *(const int4*)(ApH + kk + 32);
            }
            pbf0 = *(const float4*)(BpF + kk + 32);
            pbf1 = *(const float4*)(BpF + kk + 36);
        }

        bf16x8 af[4], bfr[2];
#pragma unroll
        for (int r = 0; r < 4; ++r)
            af[r] = *(const bf16x8*)(&As[(64 * wr + 16 * r + lm) * 40 + quad * 8]);
#pragma unroll
        for (int c = 0; c < 2; ++c)
            bfr[c] = *(const bf16x8*)(&Bs[(32 * wc + 16 * c + lm) * 40 + quad * 8]);
#pragma unroll
        for (int r = 0; r < 4; ++r)
#pragma unroll
            for (int c = 0; c < 2; ++c)
                acc[r][c] = __builtin_amdgcn_mfma_f32_16x16x32_bf16(af[r], bfr[c], acc[r][c], 0, 0, 0);
        __syncthreads();
    }

    // C/D layout: col = lane&15, row = (lane>>4)*4 + reg
#pragma unroll
    for (int r = 0; r < 4; ++r)
#pragma unroll
        for (int c = 0; c < 2; ++c)
#pragma unroll
            for (int i = 0; i < 4; ++i) {
                const int row = bm + 64 * wr + 16 * r + quad * 4 + i;
                const int col = bn + 32 * wc + 16 * c + lm;
                const float v = acc[r][c][i] + bias[col];
                if (EPI == 0) {
                    const int b = row >> 10, t = row & 1023;
                    const int s3 = col >> 10, rem = col & 1023;
                    const int h = rem >> 6, d = rem & 63;
                    const size_t base = (((size_t)s3 * 4 + b) * 16 + h) * 65536;
                    const size_t off = base + (s3 == 2 ? (size_t)d * 1024 + t
                                                       : (size_t)t * 64 + d);
                    outb[off] = f2bf(v);
                } else {
                    outf[(size_t)row * N + col] = v;
                }
            }
}

// ---------------- MFMA flash causal attention, 128-query blocks ----------------
__global__ __launch_bounds__(512) void attn_mfma(const unsigned short* __restrict__ qkvb,
                                                 const float* __restrict__ table,
                                                 unsigned short* __restrict__ y) {
    const int bh = blockIdx.x, b = bh >> 4, h = bh & 15;
    const int qb = (7 - blockIdx.y) * 128;  // longest blocks first
    const int tid = threadIdx.x, lane = tid & 63, wave = tid >> 6;
    const int quad = lane >> 4, lm = lane & 15;

    __shared__ __attribute__((aligned(16))) unsigned short Ks[64][72];      // [j][d]
    __shared__ __attribute__((aligned(16))) unsigned short Vs[64][72];      // [d][j] (V^T)
    __shared__ __attribute__((aligned(16))) unsigned short Ps[8][16][72];   // per-wave P
    __shared__ float tb[1280];

    const unsigned short* Qg  = qkvb + ((size_t)(b)*16 + h) * 65536;       // [t][d]
    const unsigned short* Kg  = qkvb + ((size_t)(4 + b)*16 + h) * 65536;   // [t][d]
    const unsigned short* Vtg = qkvb + ((size_t)(8 + b)*16 + h) * 65536;   // [d][t]

    const bf16x8 qf0 = *(const bf16x8*)(Qg + (size_t)(qb + wave * 16 + lm) * 64 + quad * 8);
    const bf16x8 qf1 = *(const bf16x8*)(Qg + (size_t)(qb + wave * 16 + lm) * 64 + 32 + quad * 8);

    const int tbn = qb + 255;
    for (int i = tid; i < tbn; i += 512) tb[i] = table[(896 + i) * 16 + h];

    f32x4 oacc[4];
#pragma unroll
    for (int nb = 0; nb < 4; ++nb) oacc[nb] = (f32x4){0.f, 0.f, 0.f, 0.f};
    float mi[4], li[4];
#pragma unroll
    for (int i = 0; i < 4; ++i) { mi[i] = -1e30f; li[i] = 0.f; }

    const int ktiles = qb / 64 + 2;
    for (int kt = 0; kt < ktiles; ++kt) {
        __syncthreads();
        {
            const int r0 = tid >> 3, c0 = (tid & 7) * 8;
            *(int4*)&Ks[r0][c0] = *(const int4*)(Kg + (size_t)(kt * 64 + r0) * 64 + c0);
            *(int4*)&Vs[r0][c0] = *(const int4*)(Vtg + (size_t)r0 * 1024 + kt * 64 + c0);
        }
        __syncthreads();

        f32x4 s[4];
#pragma unroll
        for (int nb = 0; nb < 4; ++nb) {
            bf16x8 k0 = *(const bf16x8*)(&Ks[nb * 16 + lm][quad * 8]);
            bf16x8 k1 = *(const bf16x8*)(&Ks[nb * 16 + lm][32 + quad * 8]);
            s[nb] = (f32x4){0.f, 0.f, 0.f, 0.f};
            s[nb] = __builtin_amdgcn_mfma_f32_16x16x32_bf16(qf0, k0, s[nb], 0, 0, 0);
            s[nb] = __builtin_amdgcn_mfma_f32_16x16x32_bf16(qf1, k1, s[nb], 0, 0, 0);
        }

        const int qrow0 = qb + wave * 16 + quad * 4;
        const int jbase = kt * 64 + lm;
#pragma unroll
        for (int nb = 0; nb < 4; ++nb)
#pragma unroll
            for (int i = 0; i < 4; ++i) {
                const int q = qrow0 + i, j = jbase + nb * 16;
                const float v = fmaf(s[nb][i], 0.125f, tb[q - j + 127]);
                s[nb][i] = (j <= q) ? v : -1e30f;
            }

        float mnew[4], al[4];
#pragma unroll
        for (int i = 0; i < 4; ++i) {
            float mx = fmaxf(fmaxf(s[0][i], s[1][i]), fmaxf(s[2][i], s[3][i]));
            mx = fmaxf(mx, __shfl_xor(mx, 1, 64));
            mx = fmaxf(mx, __shfl_xor(mx, 2, 64));
            mx = fmaxf(mx, __shfl_xor(mx, 4, 64));
            mx = fmaxf(mx, __shfl_xor(mx, 8, 64));
            mnew[i] = fmaxf(mi[i], mx);
            al[i] = __expf(mi[i] - mnew[i]);
            mi[i] = mnew[i];
        }
#pragma unroll
        for (int nb = 0; nb < 4; ++nb)
#pragma unroll
            for (int i = 0; i < 4; ++i) s[nb][i] = __expf(s[nb][i] - mnew[i]);
#pragma unroll
        for (int i = 0; i < 4; ++i) {
            float sm = (s[0][i] + s[1][i]) + (s[2][i] + s[3][i]);
            sm += __shfl_xor(sm, 1, 64);
            sm += __shfl_xor(sm, 2, 64);
            sm += __shfl_xor(sm, 4, 64);
            sm += __shfl_xor(sm, 8, 64);
            li[i] = li[i] * al[i] + sm;
        }

#pragma unroll
        for (int nb = 0; nb < 4; ++nb)
#pragma unroll
            for (int i = 0; i < 4; ++i)
                Ps[wave][quad * 4 + i][nb * 16 + lm] = f2bf(s[nb][i]);

#pragma unroll
        for (int nb = 0; nb < 4; ++nb)
#pragma unroll
            for (int i = 0; i < 4; ++i) oacc[nb][i] *= al[i];

        const bf16x8 p0 = *(const bf16x8*)(&Ps[wave][lm][quad * 8]);
        const bf16x8 p1 = *(const bf16x8*)(&Ps[wave][lm][32 + quad * 8]);
#pragma unroll
        for (int nb = 0; nb < 4; ++nb) {
            bf16x8 v0 = *(const bf16x8*)(&Vs[nb * 16 + lm][quad * 8]);
            bf16x8 v1 = *(const bf16x8*)(&Vs[nb * 16 + lm][32 + quad * 8]);
            oacc[nb] = __builtin_amdgcn_mfma_f32_16x16x32_bf16(p0, v0, oacc[nb], 0, 0, 0);
            oacc[nb] = __builtin_amdgcn_mfma_f32_16x16x32_bf16(p1, v1, oacc[nb], 0, 0, 0);
        }
    }

    float inv[4];
#pragma unroll
    for (int i = 0; i < 4; ++i) inv[i] = 1.0f / li[i];
#pragma unroll
    for (int nb = 0; nb < 4; ++nb)
#pragma unroll
        for (int i = 0; i < 4; ++i) {
            const int q = qb + wave * 16 + quad * 4 + i;
            const int d = nb * 16 + lm;
            y[((size_t)(b * 1024 + q)) * 1024 + h * 64 + d] = f2bf(oacc[nb][i] * inv[i]);
        }
}

extern "C" void kernel_launch(void* const* d_in, const int* in_sizes, int n_in,
                              void* d_out, int out_size, void* d_ws, size_t ws_size,
                              hipStream_t stream) {
    const float* x      = (const float*)d_in[0];
    const float* qkv_w  = (const float*)d_in[1];
    const float* qkv_b  = (const float*)d_in[2];
    const float* proj_w = (const float*)d_in[3];
    const float* proj_b = (const float*)d_in[4];
    const float* rel    = (const float*)d_in[5];
    float* out = (float*)d_out;

    char* ws = (char*)d_ws;
    float* table         = (float*)(ws + 16777216);
    unsigned short* qkvb = (unsigned short*)(ws + 16908288);
    unsigned short* yb   = (unsigned short*)(ws + 42074112);

    table_reduce<<<2047, 256, 0, stream>>>(rel, table);
    gemm_bt<0, true><<<dim3(32, 24), 512, 0, stream>>>(x, qkv_w, qkv_b, qkvb, nullptr,
                                                       4096, 3072, 1024);
    attn_mfma<<<dim3(64, 8), 512, 0, stream>>>(qkvb, table, yb);
    gemm_bt<1, false><<<dim3(32, 8), 512, 0, stream>>>(yb, proj_w, proj_b, nullptr, out,
                                                       4096, 1024, 1024);
}